// Round 7
// baseline (3408.503 us; speedup 1.0000x reference)
//
#include <hip/hip_runtime.h>
#include <hip/hip_bf16.h>
#include <math.h>

// GGNN: L=5 layers of { m = h@W_l ; agg = scatter_add(ew * m[src] -> dst) ;
//                       h = GRUCell(agg, h) } then out = relu(h)@fc_w^T + fc_b
// H=256, N=50000, E=800000.
//
// R6 lesson: glds's fixed lane->base+16i mapping with a [64][32] tile gave
// 8-way LDS read conflicts (9.6M/dispatch), and the single-buffered barrier
// serialized load latency with compute. R7: (a) stage with row=lane&15,
// kq=lane>>4 so reads land at halves cb*512+lq*128+lm*8 -> banks 4*lm%32 =
// free 2-way, zero padding; (b) double-buffer the weight LDS and prefetch
// next chunk's weights (glds) + A frags (registers) after the barrier, so
// the forced vmcnt(0) drain waits on loads issued a compute-phase earlier.

#define HDIM 256

using bf16x8 = __attribute__((ext_vector_type(8))) short;
using f32x4  = __attribute__((ext_vector_type(4))) float;

__device__ __forceinline__ bf16x8 ldfrag(const ushort* p) {
    union { uint4 u; bf16x8 f; } x;
    x.u = *(const uint4*)p;
    return x.f;
}
#define MFMA(a, b, c) __builtin_amdgcn_mfma_f32_16x16x32_bf16((a), (b), (c), 0, 0, 0)
// async global->LDS, 16B per lane; LDS dest = wave-uniform base + lane*16
#define GLD16(g, l)                                                            \
    __builtin_amdgcn_global_load_lds(                                          \
        (const __attribute__((address_space(1))) void*)(g),                    \
        (__attribute__((address_space(3))) void*)(l), 16, 0, 0)

__device__ __forceinline__ float ldf(const void* p, size_t i, int isbf) {
    if (isbf) return __bfloat162float(((const __hip_bfloat16*)p)[i]);
    return ((const float*)p)[i];
}
__device__ __forceinline__ ushort f2bs(float v) {
    __hip_bfloat16 b = __float2bfloat16(v);
    return *(ushort*)&b;
}
__device__ __forceinline__ float bs2f(ushort u) {
    __hip_bfloat16 b = *(__hip_bfloat16*)&u;
    return __bfloat162float(b);
}

// flags[0] = 1 if float tensors are bf16, 0 if f32
// flags[1] = 1 if edge_index is int64, 0 if int32
__global__ void detect_k(const void* x, const void* ei, int* flags) {
    if (blockIdx.x == 0 && threadIdx.x == 0) {
        const __hip_bfloat16* xb = (const __hip_bfloat16*)x;
        int isbf = 1;
        for (int i = 0; i < 1024; ++i) {
            float v = fabsf(__bfloat162float(xb[i]));
            if (!(v < 1e6f)) { isbf = 0; break; }
        }
        flags[0] = isbf;
        const int* e32 = (const int*)ei;
        int orv = e32[1] | e32[3] | e32[5] | e32[7] | e32[9] | e32[11];
        flags[1] = (orv == 0) ? 1 : 0;
    }
}

// x -> h hi/lo planes
__global__ void conv_h0_k(const void* x, ushort* hH, ushort* hL,
                          const int* flags, size_t n) {
    size_t i = (size_t)blockIdx.x * blockDim.x + threadIdx.x;
    if (i >= n) return;
    const float v = ldf(x, i, flags[0]);
    const ushort h = f2bs(v);
    hH[i] = h;
    hL[i] = f2bs(v - bs2f(h));
}

// Weight planes. Wt[l][j][k] = weight[l][k][j] (NT form). Wih/Whh direct
// [768][256] copies (gate order r,z,n). All split hi/lo. Biases f32.
__global__ void prep_k(const void* w, const void* wih, const void* whh,
                       const void* bih, const void* bhh,
                       ushort* WtH, ushort* WtL, ushort* WihH, ushort* WihL,
                       ushort* WhhH, ushort* WhhL,
                       float* bsum, float* bni, float* bnh,
                       const int* flags, int L) {
    int i = blockIdx.x * blockDim.x + threadIdx.x;
    int isbf = flags[0];
    if (i < L * 65536) {
        int l = i >> 16, rem = i & 65535;
        int j = rem >> 8, k = rem & 255;
        float v = ldf(w, ((size_t)l << 16) + (size_t)k * 256 + j, isbf);
        ushort h = f2bs(v);
        WtH[i] = h; WtL[i] = f2bs(v - bs2f(h));
    }
    if (i < 196608) {
        float a = ldf(wih, i, isbf);
        ushort ah = f2bs(a);
        WihH[i] = ah; WihL[i] = f2bs(a - bs2f(ah));
        float b = ldf(whh, i, isbf);
        ushort bh = f2bs(b);
        WhhH[i] = bh; WhhL[i] = f2bs(b - bs2f(bh));
    }
    if (i < 512) bsum[i] = ldf(bih, i, isbf) + ldf(bhh, i, isbf);
    if (i < 256) {
        bni[i] = ldf(bih, 512 + i, isbf);
        bnh[i] = ldf(bhh, 512 + i, isbf);
    }
}

// ---------------- CSR build (by dst), once per call ----------------

__global__ void zero_int_k(int* p, int n) {
    int i = blockIdx.x * blockDim.x + threadIdx.x;
    if (i < n) p[i] = 0;
}

__global__ void count_k(const void* ei, int* cnt, const int* flags, int E) {
    int e = blockIdx.x * blockDim.x + threadIdx.x;
    if (e >= E) return;
    const int* e32 = (const int*)ei;
    int d = flags[1] ? e32[2 * ((size_t)E + e)] : e32[(size_t)E + e];
    atomicAdd(&cnt[d], 1);
}

__global__ __launch_bounds__(256)
void scan1_k(const int* cnt, int* ptr, int* bsumN, int N) {
    __shared__ int s[256];
    const int t = threadIdx.x;
    const int gid = blockIdx.x * 256 + t;
    int v = (gid < N) ? cnt[gid] : 0;
    const int own = v;
    s[t] = v;
    __syncthreads();
#pragma unroll
    for (int off = 1; off < 256; off <<= 1) {
        int add = (t >= off) ? s[t - off] : 0;
        __syncthreads();
        s[t] += add;
        __syncthreads();
    }
    if (gid < N) ptr[gid] = s[t] - own;
    if (t == 255) bsumN[blockIdx.x] = s[255];
}

__global__ __launch_bounds__(256)
void scan2_k(int* bsumN, int NB) {
    __shared__ int s[256];
    __shared__ int carry;
    const int t = threadIdx.x;
    if (t == 0) carry = 0;
    __syncthreads();
    for (int base = 0; base < NB; base += 256) {
        const int i = base + t;
        int v = (i < NB) ? bsumN[i] : 0;
        const int own = v;
        s[t] = v;
        __syncthreads();
#pragma unroll
        for (int off = 1; off < 256; off <<= 1) {
            int add = (t >= off) ? s[t - off] : 0;
            __syncthreads();
            s[t] += add;
            __syncthreads();
        }
        if (i < NB) bsumN[i] = carry + s[t] - own;
        __syncthreads();
        if (t == 0) carry += s[255];
        __syncthreads();
    }
}

__global__ void scan3_k(int* ptr, int* cursor, const int* bsumN, int N, int E) {
    const int gid = blockIdx.x * 256 + threadIdx.x;
    if (gid < N) {
        const int p = ptr[gid] + bsumN[blockIdx.x];
        ptr[gid] = p;
        cursor[gid] = p;
    }
    if (gid == 0) ptr[N] = E;
}

__global__ void fill_k(const void* ei, const void* ew, int* cursor,
                       int* srcs, float* wse, const int* flags, int E) {
    int e = blockIdx.x * blockDim.x + threadIdx.x;
    if (e >= E) return;
    const int* e32 = (const int*)ei;
    int s, d;
    if (flags[1]) { s = e32[2 * (size_t)e]; d = e32[2 * ((size_t)E + e)]; }
    else          { s = e32[e];             d = e32[(size_t)E + e]; }
    const int p = atomicAdd(&cursor[d], 1);
    srcs[p] = s;
    wse[p] = ldf(ew, e, flags[0]);
}

// ---------------- SpMM gather: agg[d] = sum_j w_j * m[src_j] ----------------
__global__ __launch_bounds__(256)
void spmm_k(const float* __restrict__ m, const int* __restrict__ ptr,
            const int* __restrict__ srcs, const float* __restrict__ wse,
            ushort* __restrict__ aggH, ushort* __restrict__ aggL, int N) {
    const int node = blockIdx.x * 4 + (threadIdx.x >> 6);
    if (node >= N) return;
    const int lane4 = (threadIdx.x & 63) << 2;
    const int p0 = ptr[node], p1 = ptr[node + 1];
    float4 acc = make_float4(0.f, 0.f, 0.f, 0.f);
    int j = p0;
    for (; j + 1 < p1; j += 2) {
        const int s0 = srcs[j], s1 = srcs[j + 1];
        const float w0 = wse[j], w1 = wse[j + 1];
        const float4 v0 = *(const float4*)&m[(size_t)s0 * HDIM + lane4];
        const float4 v1 = *(const float4*)&m[(size_t)s1 * HDIM + lane4];
        acc.x = fmaf(w0, v0.x, acc.x); acc.y = fmaf(w0, v0.y, acc.y);
        acc.z = fmaf(w0, v0.z, acc.z); acc.w = fmaf(w0, v0.w, acc.w);
        acc.x = fmaf(w1, v1.x, acc.x); acc.y = fmaf(w1, v1.y, acc.y);
        acc.z = fmaf(w1, v1.z, acc.z); acc.w = fmaf(w1, v1.w, acc.w);
    }
    if (j < p1) {
        const int s0 = srcs[j];
        const float w0 = wse[j];
        const float4 v0 = *(const float4*)&m[(size_t)s0 * HDIM + lane4];
        acc.x = fmaf(w0, v0.x, acc.x); acc.y = fmaf(w0, v0.y, acc.y);
        acc.z = fmaf(w0, v0.z, acc.z); acc.w = fmaf(w0, v0.w, acc.w);
    }
    ushort4 hi, lo;
    hi.x = f2bs(acc.x); lo.x = f2bs(acc.x - bs2f(hi.x));
    hi.y = f2bs(acc.y); lo.y = f2bs(acc.y - bs2f(hi.y));
    hi.z = f2bs(acc.z); lo.z = f2bs(acc.z - bs2f(hi.z));
    hi.w = f2bs(acc.w); lo.w = f2bs(acc.w - bs2f(hi.w));
    *(ushort4*)&aggH[(size_t)node * HDIM + lane4] = hi;
    *(ushort4*)&aggL[(size_t)node * HDIM + lane4] = lo;
}

// ---------------- MFMA GEMMs: dbuf async-LDS weights, prefetched A ---------
// Block: 256 threads = 4 waves; tile 64 rows x 64 cols; K-chunks of 32.
// Staging (conflict-free): lane stages W[c0+w16+(lane&15)][ks+(lane>>4)*8..]
// -> LDS halves base + lane*8. Read of (col=c0+cb*16+lm, k=lq*8) lands at
// cb*512 + lq*128 + lm*8 halves -> word banks 4*lm%32: free 2-way.
// A-frag: wave-private rows, direct 16B global loads, next chunk prefetched
// into registers during compute. One barrier per chunk (double buffer).
// C/D: col = lane&15, row = (lane>>4)*4 + reg.

// m = h @ Wt^T
__global__ __launch_bounds__(256, 3)
void mfma_gemm1_k(const ushort* __restrict__ hH, const ushort* __restrict__ hL,
                  const ushort* __restrict__ WH, const ushort* __restrict__ WL,
                  float* __restrict__ m, const int* __restrict__ flags, int N) {
    __shared__ ushort smW[2 * 2048];  // 8 KB: [buf][64 cols][32 halves]
    const int tid = threadIdx.x;
    const int lane = tid & 63;
    const int wvu = __builtin_amdgcn_readfirstlane(tid >> 6);
    const int w16 = wvu * 16;
    const int r0 = blockIdx.x * 64, c0 = blockIdx.y * 64;
    const int lm = lane & 15, lq = lane >> 4;
    const int fullsplit = !flags[0];
    const int ar = min(r0 + w16 + lm, N - 1);
    const size_t wgbase = (size_t)(c0 + w16 + lm) * 256 + lq * 8;  // staging row=lm, kq=lq
    f32x4 acc[4];
#pragma unroll
    for (int cb = 0; cb < 4; ++cb) acc[cb] = (f32x4){0.f, 0.f, 0.f, 0.f};

    // prologue: stage chunk 0 + load A chunk 0
    GLD16(WH + wgbase, &smW[wvu * 512]);
    bf16x8 c_ah, c_al;
    {
        const size_t ao = (size_t)ar * 256 + lq * 8;
        c_ah = ldfrag(hH + ao);
        c_al = ldfrag(hL + ao);
    }
    for (int c = 0; c < 8; ++c) {
        const int ks = c * 32;
        __syncthreads();  // drains glds+A of chunk c (issued one phase ago)
        bf16x8 n_ah, n_al;
        if (c < 7) {
            GLD16(WH + wgbase + ks + 32, &smW[((c + 1) & 1) * 2048 + wvu * 512]);
            const size_t ao = (size_t)ar * 256 + ks + 32 + lq * 8;
            n_ah = ldfrag(hH + ao);
            n_al = ldfrag(hL + ao);
        }
        const ushort* wb0 = &smW[(c & 1) * 2048];
#pragma unroll
        for (int cb = 0; cb < 4; ++cb) {
            const bf16x8 w = ldfrag(&wb0[cb * 512 + lq * 128 + lm * 8]);
            acc[cb] = MFMA(c_ah, w, acc[cb]);
            acc[cb] = MFMA(c_al, w, acc[cb]);
            if (fullsplit) {
                const bf16x8 wl = ldfrag(&WL[(size_t)(c0 + cb * 16 + lm) * 256 + ks + lq * 8]);
                acc[cb] = MFMA(c_ah, wl, acc[cb]);
            }
        }
        if (c < 7) { c_ah = n_ah; c_al = n_al; }
    }
#pragma unroll
    for (int cb = 0; cb < 4; ++cb) {
        const int col = c0 + cb * 16 + lm;
#pragma unroll
        for (int v = 0; v < 4; ++v) {
            const int row = r0 + w16 + lq * 4 + v;
            if (row < N) m[(size_t)row * 256 + col] = acc[cb][v];
        }
    }
}

// Fused GRU gates + update. 6 weight strips double-buffered via glds
// (48 KB LDS); A planes prefetched global->register; 48 MFMAs/wave/chunk;
// epilogue does sigmoid/tanh/mix and writes h_new hi/lo planes.
__global__ __launch_bounds__(256, 3)
void mfma_gates_k(const ushort* __restrict__ agH, const ushort* __restrict__ agL,
                  const ushort* __restrict__ hoH, const ushort* __restrict__ hoL,
                  const ushort* __restrict__ WihH, const ushort* __restrict__ WihL,
                  const ushort* __restrict__ WhhH, const ushort* __restrict__ WhhL,
                  const float* __restrict__ bsum, const float* __restrict__ bni,
                  const float* __restrict__ bnh,
                  ushort* __restrict__ hnH, ushort* __restrict__ hnL,
                  const int* __restrict__ flags, int N) {
    __shared__ ushort smW[2 * 6 * 2048];  // 48 KB: [buf][strip][64 cols][32 halves]
    const int tid = threadIdx.x;
    const int lane = tid & 63;
    const int wvu = __builtin_amdgcn_readfirstlane(tid >> 6);
    const int w16 = wvu * 16;
    const int r0 = blockIdx.x * 64, c0 = blockIdx.y * 64;
    const int lm = lane & 15, lq = lane >> 4;
    const int fullsplit = !flags[0];
    const int ar = min(r0 + w16 + lm, N - 1);
    const size_t wgbase = (size_t)(c0 + w16 + lm) * 256 + lq * 8;
    f32x4 aR[4], aZ[4], aNI[4], aNH[4];
#pragma unroll
    for (int cb = 0; cb < 4; ++cb) {
        aR[cb] = (f32x4){0.f, 0.f, 0.f, 0.f};
        aZ[cb] = (f32x4){0.f, 0.f, 0.f, 0.f};
        aNI[cb] = (f32x4){0.f, 0.f, 0.f, 0.f};
        aNH[cb] = (f32x4){0.f, 0.f, 0.f, 0.f};
    }

    const ushort* Wsrc[6] = {WihH, WihH + 65536, WihH + 131072,
                             WhhH, WhhH + 65536, WhhH + 131072};
    // prologue: stage chunk 0 + load A chunk 0
#pragma unroll
    for (int j = 0; j < 6; ++j)
        GLD16(Wsrc[j] + wgbase, &smW[j * 2048 + wvu * 512]);
    bf16x8 c_ah, c_al, c_hh, c_hl;
    {
        const size_t ao = (size_t)ar * 256 + lq * 8;
        c_ah = ldfrag(agH + ao);
        c_al = ldfrag(agL + ao);
        c_hh = ldfrag(hoH + ao);
        c_hl = ldfrag(hoL + ao);
    }
    for (int c = 0; c < 8; ++c) {
        const int ks = c * 32;
        __syncthreads();  // drains glds+A of chunk c (issued one phase ago)
        bf16x8 n_ah, n_al, n_hh, n_hl;
        if (c < 7) {
            const int nb = (c + 1) & 1;
#pragma unroll
            for (int j = 0; j < 6; ++j)
                GLD16(Wsrc[j] + wgbase + ks + 32,
                      &smW[nb * 12288 + j * 2048 + wvu * 512]);
            const size_t ao = (size_t)ar * 256 + ks + 32 + lq * 8;
            n_ah = ldfrag(agH + ao);
            n_al = ldfrag(agL + ao);
            n_hh = ldfrag(hoH + ao);
            n_hl = ldfrag(hoL + ao);
        }
        const ushort* wb0 = &smW[(c & 1) * 12288];
#pragma unroll
        for (int cb = 0; cb < 4; ++cb) {
            const int wb = cb * 512 + lq * 128 + lm * 8;
            const bf16x8 wri = ldfrag(&wb0[0 * 2048 + wb]);
            const bf16x8 wzi = ldfrag(&wb0[1 * 2048 + wb]);
            const bf16x8 wni = ldfrag(&wb0[2 * 2048 + wb]);
            const bf16x8 wrh = ldfrag(&wb0[3 * 2048 + wb]);
            const bf16x8 wzh = ldfrag(&wb0[4 * 2048 + wb]);
            const bf16x8 wnh = ldfrag(&wb0[5 * 2048 + wb]);
            aR[cb] = MFMA(c_ah, wri, aR[cb]);
            aZ[cb] = MFMA(c_ah, wzi, aZ[cb]);
            aNI[cb] = MFMA(c_ah, wni, aNI[cb]);
            aNH[cb] = MFMA(c_hh, wnh, aNH[cb]);
            aR[cb] = MFMA(c_al, wri, aR[cb]);
            aZ[cb] = MFMA(c_al, wzi, aZ[cb]);
            aNI[cb] = MFMA(c_al, wni, aNI[cb]);
            aNH[cb] = MFMA(c_hl, wnh, aNH[cb]);
            aR[cb] = MFMA(c_hh, wrh, aR[cb]);
            aZ[cb] = MFMA(c_hh, wzh, aZ[cb]);
            aR[cb] = MFMA(c_hl, wrh, aR[cb]);
            aZ[cb] = MFMA(c_hl, wzh, aZ[cb]);
            if (fullsplit) {
                const size_t wr = (size_t)(c0 + cb * 16 + lm) * 256 + ks + lq * 8;
                aR[cb] = MFMA(c_ah, ldfrag(WihL + wr), aR[cb]);
                aR[cb] = MFMA(c_hh, ldfrag(WhhL + wr), aR[cb]);
                aZ[cb] = MFMA(c_ah, ldfrag(WihL + wr + 65536), aZ[cb]);
                aZ[cb] = MFMA(c_hh, ldfrag(WhhL + wr + 65536), aZ[cb]);
                aNI[cb] = MFMA(c_ah, ldfrag(WihL + wr + 131072), aNI[cb]);
                aNH[cb] = MFMA(c_hh, ldfrag(WhhL + wr + 131072), aNH[cb]);
            }
        }
        if (c < 7) { c_ah = n_ah; c_al = n_al; c_hh = n_hh; c_hl = n_hl; }
    }
#pragma unroll
    for (int cb = 0; cb < 4; ++cb) {
        const int col = c0 + cb * 16 + lm;
        const float rb = bsum[col];
        const float zb = bsum[256 + col];
        const float ib = bni[col];
        const float hb = bnh[col];
#pragma unroll
        for (int v = 0; v < 4; ++v) {
            const int row = r0 + w16 + lq * 4 + v;
            if (row < N) {
                const size_t off = (size_t)row * 256 + col;
                const float hold = bs2f(hoH[off]) + bs2f(hoL[off]);
                const float r = 1.f / (1.f + expf(-(aR[cb][v] + rb)));
                const float z = 1.f / (1.f + expf(-(aZ[cb][v] + zb)));
                const float nn = tanhf(aNI[cb][v] + ib + r * (aNH[cb][v] + hb));
                const float hv = (1.f - z) * nn + z * hold;
                const ushort hi = f2bs(hv);
                hnH[off] = hi;
                hnL[off] = f2bs(hv - bs2f(hi));
            }
        }
    }
}

// out[n] = sum_t relu(h[n,t]) * fc_w[t] + fc_b ; one 256-thread block per node
__global__ void final_k(const ushort* __restrict__ hH, const ushort* __restrict__ hL,
                        const void* fcw, const void* fcb,
                        void* out, const int* flags, int N) {
    const int n = blockIdx.x;
    const int t = threadIdx.x;
    const int isbf = flags[0];
    const size_t off = (size_t)n * HDIM + t;
    float v = fmaxf(bs2f(hH[off]) + bs2f(hL[off]), 0.f) * ldf(fcw, t, isbf);
#pragma unroll
    for (int offx = 32; offx >= 1; offx >>= 1) v += __shfl_down(v, offx);
    __shared__ float red[4];
    if ((t & 63) == 0) red[t >> 6] = v;
    __syncthreads();
    if (t == 0) {
        const float s = red[0] + red[1] + red[2] + red[3] + ldf(fcb, 0, isbf);
        if (isbf) ((__hip_bfloat16*)out)[n] = __float2bfloat16(s);
        else      ((float*)out)[n] = s;
    }
}

extern "C" void kernel_launch(void* const* d_in, const int* in_sizes, int n_in,
                              void* d_out, int out_size, void* d_ws, size_t ws_size,
                              hipStream_t stream) {
    const int H = HDIM;
    const int N = in_sizes[0] / H;       // 50000
    const int E = in_sizes[2];           // 800000
    const int L = in_sizes[3] / (H * H); // 5
    const size_t NH = (size_t)N * H;
    const int NB = (N + 255) / 256;

    char* base = (char*)d_ws;
    int*  flags = (int*)base;                         // 64 B
    char* regA  = base + 64;                          // NH*4 B (h planes / m)
    char* regB  = regA + NH * 4;                      // NH*4 B
    ushort* aggH = (ushort*)(regB + NH * 4);          // NH
    ushort* aggL = aggH + NH;                         // NH
    ushort* WtH  = aggL + NH;                         // L*65536
    ushort* WtL  = WtH + (size_t)L * 65536;
    ushort* WihH = WtL + (size_t)L * 65536;           // 196608
    ushort* WihL = WihH + 196608;
    ushort* WhhH = WihL + 196608;
    ushort* WhhL = WhhH + 196608;
    float* bsum  = (float*)(WhhL + 196608);           // 512
    float* bni   = bsum + 512;                        // 256
    float* bnh   = bni + 256;                         // 256
    int* ptr     = (int*)(bnh + 256);                 // N+1
    int* cursor  = ptr + (N + 1);                     // N
    int* bsumN   = cursor + N;                        // NB
    int* srcs    = bsumN + NB;                        // E
    float* wse   = (float*)(srcs + E);                // E
    // total ~= 165 MiB

    detect_k<<<dim3(1), dim3(64), 0, stream>>>(d_in[0], d_in[1], flags);
    conv_h0_k<<<dim3((unsigned)((NH + 255) / 256)), dim3(256), 0, stream>>>(
        d_in[0], (ushort*)regA, (ushort*)regA + NH, flags, NH);
    prep_k<<<dim3((L * 65536 + 255) / 256), dim3(256), 0, stream>>>(
        d_in[3], d_in[4], d_in[5], d_in[6], d_in[7],
        WtH, WtL, WihH, WihL, WhhH, WhhL, bsum, bni, bnh, flags, L);

    zero_int_k<<<dim3(NB), dim3(256), 0, stream>>>(cursor, N);
    count_k<<<dim3((E + 255) / 256), dim3(256), 0, stream>>>(d_in[1], cursor, flags, E);
    scan1_k<<<dim3(NB), dim3(256), 0, stream>>>(cursor, ptr, bsumN, N);
    scan2_k<<<dim3(1), dim3(256), 0, stream>>>(bsumN, NB);
    scan3_k<<<dim3(NB), dim3(256), 0, stream>>>(ptr, cursor, bsumN, N, E);
    fill_k<<<dim3((E + 255) / 256), dim3(256), 0, stream>>>(
        d_in[1], d_in[2], cursor, srcs, wse, flags, E);

    const dim3 blk(256);
    const int gm = (N + 63) / 64;
    char* regH = regA;  // current h (hi/lo planes)
    char* regM = regB;  // m (f32), later h_new planes
    for (int l = 0; l < L; ++l) {
        ushort* hH = (ushort*)regH;
        ushort* hL = hH + NH;
        mfma_gemm1_k<<<dim3(gm, 4), blk, 0, stream>>>(
            hH, hL, WtH + (size_t)l * 65536, WtL + (size_t)l * 65536,
            (float*)regM, flags, N);
        spmm_k<<<dim3((N + 3) / 4), blk, 0, stream>>>(
            (const float*)regM, ptr, srcs, wse, aggH, aggL, N);
        mfma_gates_k<<<dim3(gm, 4), blk, 0, stream>>>(
            aggH, aggL, hH, hL, WihH, WihL, WhhH, WhhL, bsum, bni, bnh,
            (ushort*)regM, (ushort*)regM + NH, flags, N);
        char* t = regH; regH = regM; regM = t;
    }
    final_k<<<dim3(N), blk, 0, stream>>>(
        (ushort*)regH, (ushort*)regH + NH, d_in[8], d_in[9], d_out, flags, N);
}

// Round 8
// 3276.657 us; speedup vs baseline: 1.0402x; 1.0402x over previous
//
#include <hip/hip_runtime.h>
#include <hip/hip_bf16.h>
#include <math.h>

// GGNN: L=5 layers of { m = h@W_l ; agg = scatter_add(ew * m[src] -> dst) ;
//                       h = GRUCell(agg, h) } then out = relu(h)@fc_w^T + fc_b
// H=256, N=50000, E=800000.
//
// R7 lesson: gates ran AT its achievable HBM bandwidth (~0.94 TB/s) because
// A-fragment loads were 16x64B gathers (row=lane&15) and the 4 col-group
// blocks re-read all A planes 4x (410MB/dispatch). R8: (1) bf16 planes stored
// in MFMA-tile layout: (n,k) -> (n>>4)*4096 + (k>>5)*512 + ((k>>3)&3)*128 +
// (n&15)*8 + (k&7), so a wave's A-frag load is one contiguous 1KB burst;
// (2) XCD swizzle bid=((r_hi*4+cg)<<3)|r_lo co-schedules the 4 col-group
// peers on one XCD so A re-reads hit that XCD's L2.

#define HDIM 256

using bf16x8 = __attribute__((ext_vector_type(8))) short;
using f32x4  = __attribute__((ext_vector_type(4))) float;

__device__ __forceinline__ bf16x8 ldfrag(const ushort* p) {
    union { uint4 u; bf16x8 f; } x;
    x.u = *(const uint4*)p;
    return x.f;
}
#define MFMA(a, b, c) __builtin_amdgcn_mfma_f32_16x16x32_bf16((a), (b), (c), 0, 0, 0)
// async global->LDS, 16B per lane; LDS dest = wave-uniform base + lane*16
#define GLD16(g, l)                                                            \
    __builtin_amdgcn_global_load_lds(                                          \
        (const __attribute__((address_space(1))) void*)(g),                    \
        (__attribute__((address_space(3))) void*)(l), 16, 0, 0)

__device__ __forceinline__ float ldf(const void* p, size_t i, int isbf) {
    if (isbf) return __bfloat162float(((const __hip_bfloat16*)p)[i]);
    return ((const float*)p)[i];
}
__device__ __forceinline__ ushort f2bs(float v) {
    __hip_bfloat16 b = __float2bfloat16(v);
    return *(ushort*)&b;
}
__device__ __forceinline__ float bs2f(ushort u) {
    __hip_bfloat16 b = *(__hip_bfloat16*)&u;
    return __bfloat162float(b);
}
// MFMA-tile layout address (elements) for plane element (n, k)
__device__ __forceinline__ size_t taddr(int n, int k) {
    return (size_t)(n >> 4) * 4096 + (size_t)((k >> 5) << 9)
         + (size_t)(((k >> 3) & 3) << 7) + (size_t)((n & 15) << 3) + (k & 7);
}

// flags[0] = 1 if float tensors are bf16, 0 if f32
// flags[1] = 1 if edge_index is int64, 0 if int32
__global__ void detect_k(const void* x, const void* ei, int* flags) {
    if (blockIdx.x == 0 && threadIdx.x == 0) {
        const __hip_bfloat16* xb = (const __hip_bfloat16*)x;
        int isbf = 1;
        for (int i = 0; i < 1024; ++i) {
            float v = fabsf(__bfloat162float(xb[i]));
            if (!(v < 1e6f)) { isbf = 0; break; }
        }
        flags[0] = isbf;
        const int* e32 = (const int*)ei;
        int orv = e32[1] | e32[3] | e32[5] | e32[7] | e32[9] | e32[11];
        flags[1] = (orv == 0) ? 1 : 0;
    }
}

// x -> h hi/lo planes (tiled layout); pad rows (n>=Nn) zeroed every call
__global__ void conv_h0_k(const void* x, ushort* hH, ushort* hL,
                          const int* flags, int Nn, size_t nhp) {
    size_t i = (size_t)blockIdx.x * blockDim.x + threadIdx.x;
    if (i >= nhp) return;
    const int n = (int)(i >> 8), k = (int)(i & 255);
    float v = 0.f;
    if (n < Nn) v = ldf(x, i, flags[0]);
    const ushort h = f2bs(v);
    const size_t a = taddr(n, k);
    hH[a] = h;
    hL[a] = f2bs(v - bs2f(h));
}

// Weight planes (row-major, NT form). Wt[l][j][k] = weight[l][k][j].
// Wih/Whh direct [768][256] copies (gate order r,z,n). Split hi/lo. Biases f32.
__global__ void prep_k(const void* w, const void* wih, const void* whh,
                       const void* bih, const void* bhh,
                       ushort* WtH, ushort* WtL, ushort* WihH, ushort* WihL,
                       ushort* WhhH, ushort* WhhL,
                       float* bsum, float* bni, float* bnh,
                       const int* flags, int L) {
    int i = blockIdx.x * blockDim.x + threadIdx.x;
    int isbf = flags[0];
    if (i < L * 65536) {
        int l = i >> 16, rem = i & 65535;
        int j = rem >> 8, k = rem & 255;
        float v = ldf(w, ((size_t)l << 16) + (size_t)k * 256 + j, isbf);
        ushort h = f2bs(v);
        WtH[i] = h; WtL[i] = f2bs(v - bs2f(h));
    }
    if (i < 196608) {
        float a = ldf(wih, i, isbf);
        ushort ah = f2bs(a);
        WihH[i] = ah; WihL[i] = f2bs(a - bs2f(ah));
        float b = ldf(whh, i, isbf);
        ushort bh = f2bs(b);
        WhhH[i] = bh; WhhL[i] = f2bs(b - bs2f(bh));
    }
    if (i < 512) bsum[i] = ldf(bih, i, isbf) + ldf(bhh, i, isbf);
    if (i < 256) {
        bni[i] = ldf(bih, 512 + i, isbf);
        bnh[i] = ldf(bhh, 512 + i, isbf);
    }
}

// ---------------- CSR build (by dst), once per call ----------------

__global__ void zero_int_k(int* p, int n) {
    int i = blockIdx.x * blockDim.x + threadIdx.x;
    if (i < n) p[i] = 0;
}

__global__ void count_k(const void* ei, int* cnt, const int* flags, int E) {
    int e = blockIdx.x * blockDim.x + threadIdx.x;
    if (e >= E) return;
    const int* e32 = (const int*)ei;
    int d = flags[1] ? e32[2 * ((size_t)E + e)] : e32[(size_t)E + e];
    atomicAdd(&cnt[d], 1);
}

__global__ __launch_bounds__(256)
void scan1_k(const int* cnt, int* ptr, int* bsumN, int N) {
    __shared__ int s[256];
    const int t = threadIdx.x;
    const int gid = blockIdx.x * 256 + t;
    int v = (gid < N) ? cnt[gid] : 0;
    const int own = v;
    s[t] = v;
    __syncthreads();
#pragma unroll
    for (int off = 1; off < 256; off <<= 1) {
        int add = (t >= off) ? s[t - off] : 0;
        __syncthreads();
        s[t] += add;
        __syncthreads();
    }
    if (gid < N) ptr[gid] = s[t] - own;
    if (t == 255) bsumN[blockIdx.x] = s[255];
}

__global__ __launch_bounds__(256)
void scan2_k(int* bsumN, int NB) {
    __shared__ int s[256];
    __shared__ int carry;
    const int t = threadIdx.x;
    if (t == 0) carry = 0;
    __syncthreads();
    for (int base = 0; base < NB; base += 256) {
        const int i = base + t;
        int v = (i < NB) ? bsumN[i] : 0;
        const int own = v;
        s[t] = v;
        __syncthreads();
#pragma unroll
        for (int off = 1; off < 256; off <<= 1) {
            int add = (t >= off) ? s[t - off] : 0;
            __syncthreads();
            s[t] += add;
            __syncthreads();
        }
        if (i < NB) bsumN[i] = carry + s[t] - own;
        __syncthreads();
        if (t == 0) carry += s[255];
        __syncthreads();
    }
}

__global__ void scan3_k(int* ptr, int* cursor, const int* bsumN, int N, int E) {
    const int gid = blockIdx.x * 256 + threadIdx.x;
    if (gid < N) {
        const int p = ptr[gid] + bsumN[blockIdx.x];
        ptr[gid] = p;
        cursor[gid] = p;
    }
    if (gid == 0) ptr[N] = E;
}

__global__ void fill_k(const void* ei, const void* ew, int* cursor,
                       int* srcs, float* wse, const int* flags, int E) {
    int e = blockIdx.x * blockDim.x + threadIdx.x;
    if (e >= E) return;
    const int* e32 = (const int*)ei;
    int s, d;
    if (flags[1]) { s = e32[2 * (size_t)e]; d = e32[2 * ((size_t)E + e)]; }
    else          { s = e32[e];             d = e32[(size_t)E + e]; }
    const int p = atomicAdd(&cursor[d], 1);
    srcs[p] = s;
    wse[p] = ldf(ew, e, flags[0]);
}

// ---------------- SpMM gather: agg[d] = sum_j w_j * m[src_j] ----------------
// agg written in tiled-plane layout.
__global__ __launch_bounds__(256)
void spmm_k(const float* __restrict__ m, const int* __restrict__ ptr,
            const int* __restrict__ srcs, const float* __restrict__ wse,
            ushort* __restrict__ aggH, ushort* __restrict__ aggL, int N) {
    const int node = blockIdx.x * 4 + (threadIdx.x >> 6);
    if (node >= N) return;
    const int lane4 = (threadIdx.x & 63) << 2;
    const int p0 = ptr[node], p1 = ptr[node + 1];
    float4 acc = make_float4(0.f, 0.f, 0.f, 0.f);
    int j = p0;
    for (; j + 1 < p1; j += 2) {
        const int s0 = srcs[j], s1 = srcs[j + 1];
        const float w0 = wse[j], w1 = wse[j + 1];
        const float4 v0 = *(const float4*)&m[(size_t)s0 * HDIM + lane4];
        const float4 v1 = *(const float4*)&m[(size_t)s1 * HDIM + lane4];
        acc.x = fmaf(w0, v0.x, acc.x); acc.y = fmaf(w0, v0.y, acc.y);
        acc.z = fmaf(w0, v0.z, acc.z); acc.w = fmaf(w0, v0.w, acc.w);
        acc.x = fmaf(w1, v1.x, acc.x); acc.y = fmaf(w1, v1.y, acc.y);
        acc.z = fmaf(w1, v1.z, acc.z); acc.w = fmaf(w1, v1.w, acc.w);
    }
    if (j < p1) {
        const int s0 = srcs[j];
        const float w0 = wse[j];
        const float4 v0 = *(const float4*)&m[(size_t)s0 * HDIM + lane4];
        acc.x = fmaf(w0, v0.x, acc.x); acc.y = fmaf(w0, v0.y, acc.y);
        acc.z = fmaf(w0, v0.z, acc.z); acc.w = fmaf(w0, v0.w, acc.w);
    }
    ushort4 hi, lo;
    hi.x = f2bs(acc.x); lo.x = f2bs(acc.x - bs2f(hi.x));
    hi.y = f2bs(acc.y); lo.y = f2bs(acc.y - bs2f(hi.y));
    hi.z = f2bs(acc.z); lo.z = f2bs(acc.z - bs2f(hi.z));
    hi.w = f2bs(acc.w); lo.w = f2bs(acc.w - bs2f(hi.w));
    const size_t a = taddr(node, lane4);  // 4 consecutive k in one octet, 8B aligned
    *(ushort4*)&aggH[a] = hi;
    *(ushort4*)&aggL[a] = lo;
}

// ---------------- MFMA GEMMs: tiled-A, dbuf glds weights, XCD swizzle -------
// 1-D grid of 4*gmp blocks; bid = ((r_hi*4+cg)<<3)|r_lo puts the 4 col-group
// peers of a row range consecutively on one XCD (bid%8 round-robin).
// A-frag load: plane + rowtile*4096 + chunk*512 + lane*8 -> contiguous 1KB.
// Weight staging (conflict-free, unchanged from R7): stage row=lane&15,
// kq=lane>>4 -> reads at cb*512+lq*128+lm*8 are free 2-way.
// C/D: col = lane&15, row = (lane>>4)*4 + reg.

// m = h @ Wt^T (m stays f32 row-major for spmm)
__global__ __launch_bounds__(256, 3)
void mfma_gemm1_k(const ushort* __restrict__ hH, const ushort* __restrict__ hL,
                  const ushort* __restrict__ WH, const ushort* __restrict__ WL,
                  float* __restrict__ m, const int* __restrict__ flags,
                  int N, int gmB) {
    __shared__ ushort smW[2 * 2048];  // 8 KB: [buf][64 cols][32 halves]
    const int bid = blockIdx.x;
    const int rlo = bid & 7, q = bid >> 3;
    const int cg = q & 3, rhi = q >> 2;
    const int rb = rhi * 8 + rlo;
    if (rb >= gmB) return;
    const int tid = threadIdx.x;
    const int lane = tid & 63;
    const int wvu = __builtin_amdgcn_readfirstlane(tid >> 6);
    const int w16 = wvu * 16;
    const int r0 = rb * 64, c0 = cg * 64;
    const int lm = lane & 15, lq = lane >> 4;
    const int fullsplit = !flags[0];
    const size_t wgbase = (size_t)(c0 + w16 + lm) * 256 + lq * 8;
    const size_t abase = (size_t)((r0 >> 4) + wvu) * 4096 + lane * 8;
    f32x4 acc[4];
#pragma unroll
    for (int cb = 0; cb < 4; ++cb) acc[cb] = (f32x4){0.f, 0.f, 0.f, 0.f};

    GLD16(WH + wgbase, &smW[wvu * 512]);
    bf16x8 c_ah = ldfrag(hH + abase);
    bf16x8 c_al = ldfrag(hL + abase);
    for (int c = 0; c < 8; ++c) {
        const int ks = c * 32;
        __syncthreads();  // drains loads issued one compute-phase ago
        bf16x8 n_ah, n_al;
        if (c < 7) {
            GLD16(WH + wgbase + ks + 32, &smW[((c + 1) & 1) * 2048 + wvu * 512]);
            const size_t ao = abase + (size_t)(c + 1) * 512;
            n_ah = ldfrag(hH + ao);
            n_al = ldfrag(hL + ao);
        }
        const ushort* wb0 = &smW[(c & 1) * 2048];
#pragma unroll
        for (int cb = 0; cb < 4; ++cb) {
            const bf16x8 w = ldfrag(&wb0[cb * 512 + lq * 128 + lm * 8]);
            acc[cb] = MFMA(c_ah, w, acc[cb]);
            acc[cb] = MFMA(c_al, w, acc[cb]);
            if (fullsplit) {
                const bf16x8 wl = ldfrag(&WL[(size_t)(c0 + cb * 16 + lm) * 256 + ks + lq * 8]);
                acc[cb] = MFMA(c_ah, wl, acc[cb]);
            }
        }
        if (c < 7) { c_ah = n_ah; c_al = n_al; }
    }
#pragma unroll
    for (int cb = 0; cb < 4; ++cb) {
        const int col = c0 + cb * 16 + lm;
#pragma unroll
        for (int v = 0; v < 4; ++v) {
            const int row = r0 + w16 + lq * 4 + v;
            if (row < N) m[(size_t)row * 256 + col] = acc[cb][v];
        }
    }
}

// Fused GRU gates + update. Tiled-A (agg/h planes), dbuf glds weights,
// 48 MFMAs/wave/chunk, epilogue sigmoid/tanh/mix, h_new tiled planes.
__global__ __launch_bounds__(256, 3)
void mfma_gates_k(const ushort* __restrict__ agH, const ushort* __restrict__ agL,
                  const ushort* __restrict__ hoH, const ushort* __restrict__ hoL,
                  const ushort* __restrict__ WihH, const ushort* __restrict__ WihL,
                  const ushort* __restrict__ WhhH, const ushort* __restrict__ WhhL,
                  const float* __restrict__ bsum, const float* __restrict__ bni,
                  const float* __restrict__ bnh,
                  ushort* __restrict__ hnH, ushort* __restrict__ hnL,
                  const int* __restrict__ flags, int N, int gmB) {
    __shared__ ushort smW[2 * 6 * 2048];  // 48 KB
    const int bid = blockIdx.x;
    const int rlo = bid & 7, q = bid >> 3;
    const int cg = q & 3, rhi = q >> 2;
    const int rb = rhi * 8 + rlo;
    if (rb >= gmB) return;
    const int tid = threadIdx.x;
    const int lane = tid & 63;
    const int wvu = __builtin_amdgcn_readfirstlane(tid >> 6);
    const int w16 = wvu * 16;
    const int r0 = rb * 64, c0 = cg * 64;
    const int lm = lane & 15, lq = lane >> 4;
    const int fullsplit = !flags[0];
    const size_t wgbase = (size_t)(c0 + w16 + lm) * 256 + lq * 8;
    const size_t abase = (size_t)((r0 >> 4) + wvu) * 4096 + lane * 8;
    f32x4 aR[4], aZ[4], aNI[4], aNH[4];
#pragma unroll
    for (int cb = 0; cb < 4; ++cb) {
        aR[cb] = (f32x4){0.f, 0.f, 0.f, 0.f};
        aZ[cb] = (f32x4){0.f, 0.f, 0.f, 0.f};
        aNI[cb] = (f32x4){0.f, 0.f, 0.f, 0.f};
        aNH[cb] = (f32x4){0.f, 0.f, 0.f, 0.f};
    }

    const ushort* Wsrc[6] = {WihH, WihH + 65536, WihH + 131072,
                             WhhH, WhhH + 65536, WhhH + 131072};
#pragma unroll
    for (int j = 0; j < 6; ++j)
        GLD16(Wsrc[j] + wgbase, &smW[j * 2048 + wvu * 512]);
    bf16x8 c_ah = ldfrag(agH + abase);
    bf16x8 c_al = ldfrag(agL + abase);
    bf16x8 c_hh = ldfrag(hoH + abase);
    bf16x8 c_hl = ldfrag(hoL + abase);
    for (int c = 0; c < 8; ++c) {
        const int ks = c * 32;
        __syncthreads();
        bf16x8 n_ah, n_al, n_hh, n_hl;
        if (c < 7) {
            const int nb = (c + 1) & 1;
#pragma unroll
            for (int j = 0; j < 6; ++j)
                GLD16(Wsrc[j] + wgbase + ks + 32,
                      &smW[nb * 12288 + j * 2048 + wvu * 512]);
            const size_t ao = abase + (size_t)(c + 1) * 512;
            n_ah = ldfrag(agH + ao);
            n_al = ldfrag(agL + ao);
            n_hh = ldfrag(hoH + ao);
            n_hl = ldfrag(hoL + ao);
        }
        const ushort* wb0 = &smW[(c & 1) * 12288];
#pragma unroll
        for (int cb = 0; cb < 4; ++cb) {
            const int wb = cb * 512 + lq * 128 + lm * 8;
            const bf16x8 wri = ldfrag(&wb0[0 * 2048 + wb]);
            const bf16x8 wzi = ldfrag(&wb0[1 * 2048 + wb]);
            const bf16x8 wni = ldfrag(&wb0[2 * 2048 + wb]);
            const bf16x8 wrh = ldfrag(&wb0[3 * 2048 + wb]);
            const bf16x8 wzh = ldfrag(&wb0[4 * 2048 + wb]);
            const bf16x8 wnh = ldfrag(&wb0[5 * 2048 + wb]);
            aR[cb] = MFMA(c_ah, wri, aR[cb]);
            aZ[cb] = MFMA(c_ah, wzi, aZ[cb]);
            aNI[cb] = MFMA(c_ah, wni, aNI[cb]);
            aNH[cb] = MFMA(c_hh, wnh, aNH[cb]);
            aR[cb] = MFMA(c_al, wri, aR[cb]);
            aZ[cb] = MFMA(c_al, wzi, aZ[cb]);
            aNI[cb] = MFMA(c_al, wni, aNI[cb]);
            aNH[cb] = MFMA(c_hl, wnh, aNH[cb]);
            aR[cb] = MFMA(c_hh, wrh, aR[cb]);
            aZ[cb] = MFMA(c_hh, wzh, aZ[cb]);
            aR[cb] = MFMA(c_hl, wrh, aR[cb]);
            aZ[cb] = MFMA(c_hl, wzh, aZ[cb]);
            if (fullsplit) {
                const size_t wr = (size_t)(c0 + cb * 16 + lm) * 256 + ks + lq * 8;
                aR[cb] = MFMA(c_ah, ldfrag(WihL + wr), aR[cb]);
                aR[cb] = MFMA(c_hh, ldfrag(WhhL + wr), aR[cb]);
                aZ[cb] = MFMA(c_ah, ldfrag(WihL + wr + 65536), aZ[cb]);
                aZ[cb] = MFMA(c_hh, ldfrag(WhhL + wr + 65536), aZ[cb]);
                aNI[cb] = MFMA(c_ah, ldfrag(WihL + wr + 131072), aNI[cb]);
                aNH[cb] = MFMA(c_hh, ldfrag(WhhL + wr + 131072), aNH[cb]);
            }
        }
        if (c < 7) { c_ah = n_ah; c_al = n_al; c_hh = n_hh; c_hl = n_hl; }
    }
#pragma unroll
    for (int cb = 0; cb < 4; ++cb) {
        const int col = c0 + cb * 16 + lm;
        const float rb_ = bsum[col];
        const float zb = bsum[256 + col];
        const float ib = bni[col];
        const float hb = bnh[col];
#pragma unroll
        for (int v = 0; v < 4; ++v) {
            const int row = r0 + w16 + lq * 4 + v;
            if (row < N) {
                const size_t off = taddr(row, col);
                const float hold = bs2f(hoH[off]) + bs2f(hoL[off]);
                const float r = 1.f / (1.f + expf(-(aR[cb][v] + rb_)));
                const float z = 1.f / (1.f + expf(-(aZ[cb][v] + zb)));
                const float nn = tanhf(aNI[cb][v] + ib + r * (aNH[cb][v] + hb));
                const float hv = (1.f - z) * nn + z * hold;
                const ushort hi = f2bs(hv);
                hnH[off] = hi;
                hnL[off] = f2bs(hv - bs2f(hi));
            }
        }
    }
}

// out[n] = sum_t relu(h[n,t]) * fc_w[t] + fc_b ; one 256-thread block per node
__global__ void final_k(const ushort* __restrict__ hH, const ushort* __restrict__ hL,
                        const void* fcw, const void* fcb,
                        void* out, const int* flags, int N) {
    const int n = blockIdx.x;
    const int t = threadIdx.x;
    const int isbf = flags[0];
    const size_t off = taddr(n, t);
    float v = fmaxf(bs2f(hH[off]) + bs2f(hL[off]), 0.f) * ldf(fcw, t, isbf);
#pragma unroll
    for (int offx = 32; offx >= 1; offx >>= 1) v += __shfl_down(v, offx);
    __shared__ float red[4];
    if ((t & 63) == 0) red[t >> 6] = v;
    __syncthreads();
    if (t == 0) {
        const float s = red[0] + red[1] + red[2] + red[3] + ldf(fcb, 0, isbf);
        if (isbf) ((__hip_bfloat16*)out)[n] = __float2bfloat16(s);
        else      ((float*)out)[n] = s;
    }
}

extern "C" void kernel_launch(void* const* d_in, const int* in_sizes, int n_in,
                              void* d_out, int out_size, void* d_ws, size_t ws_size,
                              hipStream_t stream) {
    const int H = HDIM;
    const int N = in_sizes[0] / H;       // 50000
    const int E = in_sizes[2];           // 800000
    const int L = in_sizes[3] / (H * H); // 5
    const size_t NH = (size_t)N * H;
    const int NB = (N + 255) / 256;
    const int gmB = (N + 63) / 64;       // 782 row-blocks
    const int gmp = ((gmB + 7) / 8) * 8; // 784 (pad for swizzle decode)
    const size_t NHP = (size_t)gmB * 64 * 256;  // padded plane elems (50048*256)

    char* base = (char*)d_ws;
    int*  flags = (int*)base;                         // 64 B
    char* regA  = base + 64;                          // NHP*4 B (h planes / m)
    char* regB  = regA + NHP * 4;                     // NHP*4 B
    ushort* aggH = (ushort*)(regB + NHP * 4);         // NHP
    ushort* aggL = aggH + NHP;                        // NHP
    ushort* WtH  = aggL + NHP;                        // L*65536
    ushort* WtL  = WtH + (size_t)L * 65536;
    ushort* WihH = WtL + (size_t)L * 65536;           // 196608
    ushort* WihL = WihH + 196608;
    ushort* WhhH = WihL + 196608;
    ushort* WhhL = WhhH + 196608;
    float* bsum  = (float*)(WhhL + 196608);           // 512
    float* bni   = bsum + 512;                        // 256
    float* bnh   = bni + 256;                         // 256
    int* ptr     = (int*)(bnh + 256);                 // N+1
    int* cursor  = ptr + (N + 1);                     // N
    int* bsumN   = cursor + N;                        // NB
    int* srcs    = bsumN + NB;                        // E
    float* wse   = (float*)(srcs + E);                // E
    // total ~= 166 MiB

    detect_k<<<dim3(1), dim3(64), 0, stream>>>(d_in[0], d_in[1], flags);
    conv_h0_k<<<dim3((unsigned)((NHP + 255) / 256)), dim3(256), 0, stream>>>(
        d_in[0], (ushort*)regA, (ushort*)regA + NHP, flags, N, NHP);
    prep_k<<<dim3((L * 65536 + 255) / 256), dim3(256), 0, stream>>>(
        d_in[3], d_in[4], d_in[5], d_in[6], d_in[7],
        WtH, WtL, WihH, WihL, WhhH, WhhL, bsum, bni, bnh, flags, L);

    zero_int_k<<<dim3(NB), dim3(256), 0, stream>>>(cursor, N);
    count_k<<<dim3((E + 255) / 256), dim3(256), 0, stream>>>(d_in[1], cursor, flags, E);
    scan1_k<<<dim3(NB), dim3(256), 0, stream>>>(cursor, ptr, bsumN, N);
    scan2_k<<<dim3(1), dim3(256), 0, stream>>>(bsumN, NB);
    scan3_k<<<dim3(NB), dim3(256), 0, stream>>>(ptr, cursor, bsumN, N, E);
    fill_k<<<dim3((E + 255) / 256), dim3(256), 0, stream>>>(
        d_in[1], d_in[2], cursor, srcs, wse, flags, E);

    const dim3 blk(256);
    const unsigned grid2 = (unsigned)(4 * gmp);
    char* regH = regA;  // current h (hi/lo planes)
    char* regM = regB;  // m (f32), later h_new planes
    for (int l = 0; l < L; ++l) {
        ushort* hH = (ushort*)regH;
        ushort* hL = hH + NHP;
        mfma_gemm1_k<<<dim3(grid2), blk, 0, stream>>>(
            hH, hL, WtH + (size_t)l * 65536, WtL + (size_t)l * 65536,
            (float*)regM, flags, N, gmB);
        spmm_k<<<dim3((N + 3) / 4), blk, 0, stream>>>(
            (const float*)regM, ptr, srcs, wse, aggH, aggL, N);
        mfma_gates_k<<<dim3(grid2), blk, 0, stream>>>(
            aggH, aggL, hH, hL, WihH, WihL, WhhH, WhhL, bsum, bni, bnh,
            (ushort*)regM, (ushort*)regM + NHP, flags, N, gmB);
        char* t = regH; regH = regM; regM = t;
    }
    final_k<<<dim3(N), blk, 0, stream>>>(
        (ushort*)regH, (ushort*)regH + NHP, d_in[8], d_in[9], d_out, flags, N);
}